// Round 3
// 352.411 us; speedup vs baseline: 1.0297x; 1.0297x over previous
//
#include <hip/hip_runtime.h>

// BackEdgeConv2d: out = x * !(5 <= boxsum7x7(x >= 128/255, reflect-pad) <= 19)
// x: [16, 3, 1024, 1024] fp32.  Streaming stencil, HBM-bound in the limit.
//
// R5 == R4 with compile fix: __builtin_nontemporal_store requires a native
// clang vector type, not HIP's float4 class -> store via
// ext_vector_type(4) float alias (same global_store_dwordx4 nt).
//
// R3 theory (vs R2: 141us dispatch, 3.37 TB/s, VALUBusy 17%, VGPR 52):
// latency-bound -- zero prefetch distance + dependent output-phase re-read.
//  - 5-deep register ring of raw rows (slots s-3..s+1): row s+1 issued
//    before row s is consumed (distance-1 prefetch); output pass-through x
//    comes from ring slot s-3 instead of a re-read.
//  - BH 8->16: halo overhead 1.75x -> 1.375x row-reads; 768 wgs = 3/CU exact.
//  - nibble-packed horizontal-sum ring (h<=7 fits 4 bits; 2 u32/step) keeps
//    the live set ~120 VGPRs; launch_bounds(256,3) = what the grid can use.
//  - nontemporal stores: output never re-read; preserve L2/LLC for halo.
//
// Layout per wave (verified R2): lane i owns one float4 per quarter-row
// (cols 256q+4i..+3) -> every load/store is a wave-contiguous 1KB
// transaction. Horizontal 7-sums via shfl neighbors + popc; vertical 7-row
// sliding sum in byte-packed u32s. No LDS, no barriers.

constexpr int H = 1024;
constexpr int W = 1024;
constexpr int BH = 16;           // rows per band (per wave)
constexpr int NBANDS = H / BH;   // 64
constexpr int STEPS = BH + 6;    // 22 stencil rows per band
constexpr int D = 5;             // row ring depth: slots s-3 .. s+1

typedef float vfloat4 __attribute__((ext_vector_type(4)));

__device__ __forceinline__ void nt_store4(float* p, float4 v) {
    vfloat4 t;
    t.x = v.x; t.y = v.y; t.z = v.z; t.w = v.w;
    __builtin_nontemporal_store(t, (vfloat4*)p);
}

__device__ __forceinline__ unsigned expand4(unsigned n) {
    // 4 nibbles (in a u16) -> 4 bytes
    unsigned t = (n | (n << 8)) & 0x00FF00FFu;
    return (t | (t << 4)) & 0x0F0F0F0Fu;
}
__device__ __forceinline__ unsigned compress4(unsigned b) {
    // 4 bytes (each <= 15) -> 4 nibbles (u16)
    unsigned t = (b | (b >> 4)) & 0x00FF00FFu;
    return (t | (t >> 8)) & 0x0000FFFFu;
}

__global__ __launch_bounds__(256, 3)
void backedge_kernel(const float* __restrict__ x, float* __restrict__ out) {
    const int lane = threadIdx.x & 63;
    const int wv   = threadIdx.x >> 6;            // 0..3, independent waves
    const int band = blockIdx.x * 4 + wv;         // 0..63
    const int n    = blockIdx.y;                  // 0..47 (B*C)
    const int r0   = band * BH;
    const float* __restrict__ xi = x   + (size_t)n * (size_t)(H * W);
    float*       __restrict__ oi = out + (size_t)n * (size_t)(H * W);
    const int off = 4 * lane;                     // float offset inside a quarter
    const float THR = 128.0f / 255.0f;

    float4 ring[D][4];                            // raw rows, 80 VGPRs
    unsigned int hn[7][2];                        // nibble-packed h-sums, 14 VGPRs
#pragma unroll
    for (int i = 0; i < 7; ++i) { hn[i][0] = 0u; hn[i][1] = 0u; }
    unsigned int vs[4] = {0u, 0u, 0u, 0u};        // byte-packed vertical sums

    // prologue: issue loads for step 0 (row reflect(r0-3))
    {
        int g = r0 - 3;
        g = (g < 0) ? -g : g;                     // only top reflect possible here
        const float* rp = xi + (size_t)g * W;
#pragma unroll
        for (int q = 0; q < 4; ++q)
            ring[0][q] = *(const float4*)(rp + q * 256 + off);
    }

#pragma unroll
    for (int s = 0; s < STEPS; ++s) {
        // ---- prefetch row s+1 into ring slot (s+1)%D (issued before the
        //      wait on row s's data; slot last read at output step s-1) ----
        if (s + 1 < STEPS) {
            int g = r0 - 3 + (s + 1);
            g = (g < 0) ? -g : g;                 // reflect top
            g = (g >= H) ? (2 * H - 2 - g) : g;   // reflect bottom
            const float* rp = xi + (size_t)g * W;
#pragma unroll
            for (int q = 0; q < 4; ++q)
                ring[(s + 1) % D][q] = *(const float4*)(rp + q * 256 + off);
        }

        // ---- 16 threshold bits from row s: bit 4q+j <-> col 256q+4*lane+j ----
        unsigned int m = 0;
#pragma unroll
        for (int q = 0; q < 4; ++q) {
            const float4 aq = ring[s % D][q];
            m |= ((unsigned)(aq.x >= THR)) << (4 * q + 0);
            m |= ((unsigned)(aq.y >= THR)) << (4 * q + 1);
            m |= ((unsigned)(aq.z >= THR)) << (4 * q + 2);
            m |= ((unsigned)(aq.w >= THR)) << (4 * q + 3);
        }

        const unsigned int up = __shfl_up(m, 1);    // lane i-1's mask
        const unsigned int dn = __shfl_down(m, 1);  // lane i+1's mask
        const unsigned int hi = __shfl(m, 63);      // lane 63 broadcast
        const unsigned int lo = __shfl(m, 0);       // lane 0 broadcast
        // left-neighbor source: quarter q of SL supplies cols 256q+4i-4..-1
        const unsigned int SL = (lane == 0) ? (hi << 4) : up;
        // right-neighbor source: quarter q of SR supplies cols 256q+4i+4..+7
        const unsigned int SR = (lane == 63) ? (lo >> 4) : dn;

        unsigned int hp[4];
#pragma unroll
        for (int q = 0; q < 4; ++q) {
            // w bit k <-> col (256q + 4*lane) + k - 3   (10 bits used)
            unsigned int w = ((SL >> (4 * q + 1)) & 7u)
                           | (((m >> (4 * q)) & 0xFu) << 3)
                           | (((SR >> (4 * q)) & 7u) << 7);
            if (q == 0 && lane == 0) {
                // cols -3,-2,-1 reflect -> cols 3,2,1 (own bits 3,2,1)
                w |= ((m >> 3) & 1u) | (((m >> 2) & 1u) << 1)
                   | (((m >> 1) & 1u) << 2);
            }
            if (q == 3 && lane == 63) {
                // cols 1024,1025,1026 reflect -> 1022,1021,1020 (bits 14,13,12)
                w |= (((m >> 14) & 1u) << 7) | (((m >> 13) & 1u) << 8)
                   | (((m >> 12) & 1u) << 9);
            }
            const unsigned int h0 = __popc((w >> 0) & 0x7Fu);
            const unsigned int h1 = __popc((w >> 1) & 0x7Fu);
            const unsigned int h2 = __popc((w >> 2) & 0x7Fu);
            const unsigned int h3 = __popc((w >> 3) & 0x7Fu);
            hp[q] = h0 | (h1 << 8) | (h2 << 16) | (h3 << 24);
        }

        // ---- vertical sliding sum (byte digits <= 49, never carry) ----
        vs[0] += hp[0] - expand4(hn[0][0] & 0xFFFFu);
        vs[1] += hp[1] - expand4(hn[0][0] >> 16);
        vs[2] += hp[2] - expand4(hn[0][1] & 0xFFFFu);
        vs[3] += hp[3] - expand4(hn[0][1] >> 16);
#pragma unroll
        for (int i = 0; i < 6; ++i) {
            hn[i][0] = hn[i + 1][0];
            hn[i][1] = hn[i + 1][1];
        }
        hn[6][0] = compress4(hp[0]) | (compress4(hp[1]) << 16);
        hn[6][1] = compress4(hp[2]) | (compress4(hp[3]) << 16);

        // ---- output row r0+s-6; its raw x lives in ring slot s-3 ----
        if (s >= 6) {
            const int orow = r0 + s - 6;
            float* op = oi + (size_t)orow * W;
#pragma unroll
            for (int q = 0; q < 4; ++q) {
                const float4 b = ring[(s - 3) % D][q];
                const unsigned int v = vs[q];
                float4 o;
                // zeroed iff 5 <= csum <= 19  <=>  (csum-5) <= 14 unsigned
                o.x = ((((v      ) & 0xFFu) - 5u) <= 14u) ? 0.0f : b.x;
                o.y = ((((v >>  8) & 0xFFu) - 5u) <= 14u) ? 0.0f : b.y;
                o.z = ((((v >> 16) & 0xFFu) - 5u) <= 14u) ? 0.0f : b.z;
                o.w = ((((v >> 24)        ) - 5u) <= 14u) ? 0.0f : b.w;
                nt_store4(op + q * 256 + off, o);
            }
        }
    }
}

extern "C" void kernel_launch(void* const* d_in, const int* in_sizes, int n_in,
                              void* d_out, int out_size, void* d_ws, size_t ws_size,
                              hipStream_t stream) {
    const float* x = (const float*)d_in[0];
    float* out = (float*)d_out;
    (void)in_sizes; (void)n_in; (void)d_ws; (void)ws_size; (void)out_size;
    dim3 grid(NBANDS / 4, 16 * 3);   // 16 x 48 = 768 blocks of 256 (4 waves/block)
    backedge_kernel<<<grid, dim3(256), 0, stream>>>(x, out);
}